// Round 9
// baseline (364.629 us; speedup 1.0000x reference)
//
#include <hip/hip_runtime.h>
#include <hip/hip_bf16.h>
#include <cstddef>

// ---------------------------------------------------------------------------
// 3-layer MPNN, N=50000, E=800000, D=128, OUT=32.
// R9: (a) bin rewritten as LDS multi-split: per-block LDS histogram over the
// 391 dst-buckets + ONE global run-reservation atomic per (block,bucket)
// (~150k atomics vs 800k; R8 evidence: per-edge device-scope atomics were
// the cost, not line placement). (b) aggregate split into two 64-feature
// passes so the gather working set (6.4 MB/pass) fits per-XCD L2.
//   g = Sigma_in w*h[src]; h' = tanh([g|h]@[Wm;Wu]^T+bu); out = h3@Wout^T+b.
// CSR entry: (src:u16 | w:bf16<<16). Staged: one region per bucket, CAPB.
// ---------------------------------------------------------------------------

typedef __attribute__((ext_vector_type(8))) short short8;
typedef __attribute__((ext_vector_type(4))) float f32x4;
typedef unsigned short ushort_t;
typedef unsigned int uint_t;

#define CAPB 4096           // staged entries per bucket (max bucket ~2.3k)
#define TSTRIDE 16          // tails counter stride in ints (64B line each)
#define EPB 2048            // edges per bin block

__device__ inline ushort_t f2bf(float f) {  // round-to-nearest-even
    uint_t u = __float_as_uint(f);
    uint_t r = u + 0x7FFFu + ((u >> 16) & 1u);
    return (ushort_t)(r >> 16);
}
__device__ inline float bf_lo(uint_t u) { return __uint_as_float(u << 16); }
__device__ inline float bf_hi(uint_t u) { return __uint_as_float(u & 0xFFFF0000u); }
__device__ inline uint_t packbf(float a, float b) {
    return (uint_t)f2bf(a) | ((uint_t)f2bf(b) << 16);
}

// flag=1 -> int32 [2][E]; flag=0 -> int64 [2][E] (vectorized low-word read)
__device__ inline int get_dst(const int* __restrict__ ei, int e, int E, int f) {
    if (f) return ei[E + e];
    return ((const int2*)ei)[(size_t)E + e].x;
}
__device__ inline int get_src(const int* __restrict__ ei, int e, int E, int f) {
    if (f) return ei[e];
    return ((const int2*)ei)[e].x;
}

// ---------------------------------------------------------------------------
// Fused setup: zero bucket tails | detect idx layout | bf16 Wcat + Wout |
// x -> bf16.
// ---------------------------------------------------------------------------
struct SetupArgs {
    const float* Wm0; const float* Wu0;
    const float* Wm1; const float* Wu1;
    const float* Wm2; const float* Wu2;
    const float* Wout;
    const float* x; const int* ei;
    ushort_t* wcat;    // 3 * 128*256
    ushort_t* woutb;   // 32*128
    ushort_t* xb;      // N*128
    int* tails;        // NB counters, stride TSTRIDE ints
    int* flag;
    int N, E, TI;
    int ZT, WB, XB;
};
__global__ __launch_bounds__(256) void setup_kernel(SetupArgs a) {
    int bx = blockIdx.x, t = threadIdx.x;
    if (bx < a.ZT) {
        int i = bx * 256 + t;
        if (i < a.TI) a.tails[i] = 0;
        return;
    }
    bx -= a.ZT;
    if (bx == 0) {
        __shared__ int any;
        if (t == 0) any = 0;
        __syncthreads();
        int n = a.E < 2048 ? a.E : 2048;
        for (int i = t; i < n; i += 256)
            if (a.ei[2 * i + 1] != 0) any = 1;
        __syncthreads();
        if (t == 0) a.flag[0] = any;
        return;
    }
    bx -= 1;
    if (bx < a.WB) {
        int i = bx * 256 + t;
        if (i < 3 * 32768) {
            int l = i >> 15, rem = i & 32767, r = rem >> 8, k = rem & 255;
            const float* Wm = l == 0 ? a.Wm0 : (l == 1 ? a.Wm1 : a.Wm2);
            const float* Wu = l == 0 ? a.Wu0 : (l == 1 ? a.Wu1 : a.Wu2);
            float v = k < 128 ? Wm[r * 128 + k] : Wu[r * 128 + (k - 128)];
            a.wcat[(size_t)l * 32768 + r * 256 + k] = f2bf(v);
        } else if (i < 3 * 32768 + 4096) {
            int j = i - 3 * 32768;
            a.woutb[j] = f2bf(a.Wout[j]);
        }
        return;
    }
    bx -= a.WB;
    {
        int j = bx * 256 + t;
        if (j < a.N * 32) {
            float4 v = *(const float4*)(a.x + (size_t)j * 4);
            uint2 o;
            o.x = packbf(v.x, v.y);
            o.y = packbf(v.z, v.w);
            *(uint2*)(a.xb + (size_t)j * 4) = o;
        }
    }
}

// ---------------------------------------------------------------------------
// Phase A: LDS multi-split binning. Block stages EPB edges in LDS, builds an
// LDS histogram over buckets (b = dst>>7), reserves ONE contiguous run per
// non-empty bucket via a single global atomic, then writes each run into the
// bucket's staged region (consecutive slots, same CU -> line-local).
// ---------------------------------------------------------------------------
__global__ __launch_bounds__(256) void bin_kernel(
    const int* __restrict__ ei, const float* __restrict__ ew,
    const int* __restrict__ flag, int* __restrict__ tails,
    uint2* __restrict__ staged, int E, int NB) {
    __shared__ uint2 ent[EPB];           // 16 KB
    __shared__ int cnt[512], cur[512], runbase[512];
    const int tid = threadIdx.x;
    const int e0 = blockIdx.x * EPB;
    const int nE = (E - e0) < EPB ? (E - e0) : EPB;
    const int f = flag[0];
    for (int b = tid; b < 512; b += 256) { cnt[b] = 0; cur[b] = 0; }
    __syncthreads();
    for (int i = tid; i < nE; i += 256) {
        int e = e0 + i;
        int s = get_src(ei, e, E, f);
        int d = get_dst(ei, e, E, f);
        uint2 v;
        v.x = (uint_t)s | ((uint_t)f2bf(ew[e]) << 16);
        v.y = (uint_t)d;
        ent[i] = v;
        atomicAdd(&cnt[d >> 7], 1);      // LDS atomic
    }
    __syncthreads();
    for (int b = tid; b < NB; b += 256) {
        int c = cnt[b];
        runbase[b] = c ? atomicAdd(&tails[b * TSTRIDE], c) : 0;
    }
    __syncthreads();
    for (int i = tid; i < nE; i += 256) {
        uint2 v = ent[i];
        int d = (int)v.y;
        int b = d >> 7;
        int lp = atomicAdd(&cur[b], 1);  // LDS atomic
        int gp = runbase[b] + lp;
        if (gp < CAPB) {
            uint2 o;
            o.x = v.x;
            o.y = (uint_t)(d & 127);
            staged[(size_t)b * CAPB + gp] = o;
        }
    }
}

// exclusive scan of per-bucket totals -> csrBase[NB]. NB<=512, one block.
__global__ __launch_bounds__(512) void bucket_scan(
    const int* __restrict__ tails, int* __restrict__ csrBase, int NB) {
    __shared__ int sm[512];
    int t = threadIdx.x;
    int s = 0;
    if (t < NB) {
        int c = tails[t * TSTRIDE];
        s = c < CAPB ? c : CAPB;
    }
    sm[t] = s;
    __syncthreads();
    for (int o = 1; o < 512; o <<= 1) {
        int v = t >= o ? sm[t - o] : 0;
        __syncthreads();
        sm[t] += v;
        __syncthreads();
    }
    if (t < NB) csrBase[t] = sm[t] - s;
}

// ---------------------------------------------------------------------------
// Phase B: one block per bucket. LDS hist (128 nodes) -> LDS excl scan ->
// place into LDS image of the bucket's contiguous CSR range -> coalesced
// flush. Writes deg[] and rowend[].
// ---------------------------------------------------------------------------
__global__ __launch_bounds__(256) void place_kernel(
    const uint2* __restrict__ staged, const int* __restrict__ tails,
    const int* __restrict__ csrBase, uint_t* __restrict__ csr,
    int* __restrict__ rowend, int* __restrict__ deg, int N) {
    __shared__ int cnt[128], cur[128], excl[128], sm[256];
    __shared__ uint_t outb[CAPB];        // 16 KB
    const int b = blockIdx.x, tid = threadIdx.x;
    const int node0 = b << 7;
    const int base = csrBase[b];
    int tot = tails[b * TSTRIDE];
    tot = tot < CAPB ? tot : CAPB;
    if (tid < 128) cnt[tid] = 0;
    __syncthreads();
    const uint2* sp = staged + ((size_t)b * CAPB);
    for (int i = tid; i < tot; i += 256) atomicAdd(&cnt[sp[i].y], 1);
    __syncthreads();
    int c0 = tid < 128 ? cnt[tid] : 0;
    sm[tid] = c0;
    __syncthreads();
    for (int o = 1; o < 256; o <<= 1) {
        int v = tid >= o ? sm[tid - o] : 0;
        __syncthreads();
        sm[tid] += v;
        __syncthreads();
    }
    if (tid < 128) {
        excl[tid] = sm[tid] - c0;
        cur[tid] = 0;
    }
    __syncthreads();
    for (int i = tid; i < tot; i += 256) {
        uint2 e = sp[i];
        int pos = excl[e.y] + atomicAdd(&cur[e.y], 1);
        outb[pos] = e.x;
    }
    __syncthreads();
    for (int i = tid; i < tot; i += 256) csr[base + i] = outb[i];
    if (tid < 128 && node0 + tid < N) {
        deg[node0 + tid] = c0;
        rowend[node0 + tid] = base + excl[tid] + c0;
    }
}

// ---------------------------------------------------------------------------
// Aggregate (64-feature half): g[d, foff:foff+64] = Sigma w*h[src, foff:..].
// One 64-lane wave per node; lane = slot(0..7)*8 + f8(0..7); lane loads one
// uint4 (8 bf16 feats). Two passes (foff 0, 64) keep the gather working set
// at 6.4 MB (2 lines of each 256B row) -> per-XCD L2 resident.
// ---------------------------------------------------------------------------
__global__ __launch_bounds__(256) void aggregate_h(
    const uint_t* __restrict__ csr, const int* __restrict__ rowend,
    const int* __restrict__ deg, const ushort_t* __restrict__ h,
    ushort_t* __restrict__ g, int N, int foff) {
    int node = (blockIdx.x * 256 + threadIdx.x) >> 6;
    if (node >= N) return;
    int lane = threadIdx.x & 63;
    int slot = lane >> 3, f8 = lane & 7;
    int end = rowend[node];
    int beg = end - deg[node];
    float s0 = 0.f, s1 = 0.f, s2 = 0.f, s3 = 0.f;
    float s4 = 0.f, s5 = 0.f, s6 = 0.f, s7 = 0.f;
    for (int j = beg + slot; j < end; j += 8) {
        uint_t p = csr[j];
        float w = bf_hi(p);
        uint4 v = *(const uint4*)(h + (size_t)(p & 0xFFFFu) * 128 + foff + f8 * 8);
        s0 += w * bf_lo(v.x); s1 += w * bf_hi(v.x);
        s2 += w * bf_lo(v.y); s3 += w * bf_hi(v.y);
        s4 += w * bf_lo(v.z); s5 += w * bf_hi(v.z);
        s6 += w * bf_lo(v.w); s7 += w * bf_hi(v.w);
    }
    s0 += __shfl_xor(s0, 8, 64);  s1 += __shfl_xor(s1, 8, 64);
    s2 += __shfl_xor(s2, 8, 64);  s3 += __shfl_xor(s3, 8, 64);
    s4 += __shfl_xor(s4, 8, 64);  s5 += __shfl_xor(s5, 8, 64);
    s6 += __shfl_xor(s6, 8, 64);  s7 += __shfl_xor(s7, 8, 64);
    s0 += __shfl_xor(s0, 16, 64); s1 += __shfl_xor(s1, 16, 64);
    s2 += __shfl_xor(s2, 16, 64); s3 += __shfl_xor(s3, 16, 64);
    s4 += __shfl_xor(s4, 16, 64); s5 += __shfl_xor(s5, 16, 64);
    s6 += __shfl_xor(s6, 16, 64); s7 += __shfl_xor(s7, 16, 64);
    s0 += __shfl_xor(s0, 32, 64); s1 += __shfl_xor(s1, 32, 64);
    s2 += __shfl_xor(s2, 32, 64); s3 += __shfl_xor(s3, 32, 64);
    s4 += __shfl_xor(s4, 32, 64); s5 += __shfl_xor(s5, 32, 64);
    s6 += __shfl_xor(s6, 32, 64); s7 += __shfl_xor(s7, 32, 64);
    if (slot == 0) {
        uint4 o;
        o.x = packbf(s0, s1);
        o.y = packbf(s2, s3);
        o.z = packbf(s4, s5);
        o.w = packbf(s6, s7);
        *(uint4*)(g + (size_t)node * 128 + foff + f8 * 8) = o;
    }
}

// ---------------------------------------------------------------------------
// Fused layer GEMM: Hout[N,128] = tanh([G|H][N,256] @ Wcat[128,256]^T + bu)
// BM=64, BN=128; LDS chunk layout (lane-contiguous 16B, conflict-free).
// ---------------------------------------------------------------------------
__global__ __launch_bounds__(256) void fused_gemm(
    const ushort_t* __restrict__ G, const ushort_t* __restrict__ H,
    const ushort_t* __restrict__ Wcat, const float* __restrict__ bias,
    ushort_t* __restrict__ Hout, int N) {
    __shared__ short As[64 * 128];    // 16 KB
    __shared__ short Ws[128 * 128];   // 32 KB
    const int tid = threadIdx.x;
    const int row0 = blockIdx.x * 64;
    const int wv = tid >> 6, lane = tid & 63;
    const int rt = wv;

    f32x4 acc[8];
#pragma unroll
    for (int ct = 0; ct < 8; ++ct) acc[ct] = (f32x4){0.f, 0.f, 0.f, 0.f};

#pragma unroll
    for (int chunk = 0; chunk < 2; ++chunk) {
        const ushort_t* A = chunk ? H : G;
        const int kco = chunk * 128;
        if (chunk) __syncthreads();
#pragma unroll
        for (int it = 0; it < 4; ++it) {
            int c = tid + 256 * it;
            int mm = c & 15, q = (c >> 4) & 3, ks = (c >> 6) & 3, rtile = c >> 8;
            int gr = row0 + rtile * 16 + mm;
            short8 v = {0, 0, 0, 0, 0, 0, 0, 0};
            if (gr < N) v = *(const short8*)(A + (size_t)gr * 128 + ks * 32 + q * 8);
            *(short8*)&As[c * 8] = v;
        }
#pragma unroll
        for (int it = 0; it < 8; ++it) {
            int c = tid + 256 * it;
            int mm = c & 15, q = (c >> 4) & 3, ks = (c >> 6) & 3, ct = c >> 8;
            *(short8*)&Ws[c * 8] =
                *(const short8*)(Wcat + (size_t)(ct * 16 + mm) * 256 + kco + ks * 32 + q * 8);
        }
        __syncthreads();
#pragma unroll
        for (int ks = 0; ks < 4; ++ks) {
            short8 a = *(const short8*)&As[((rt * 4 + ks) * 64 + lane) * 8];
#pragma unroll
            for (int ct = 0; ct < 8; ++ct) {
                short8 b = *(const short8*)&Ws[((ct * 4 + ks) * 64 + lane) * 8];
                acc[ct] = __builtin_amdgcn_mfma_f32_16x16x32_bf16(a, b, acc[ct], 0, 0, 0);
            }
        }
    }
    const int colL = lane & 15, rq = lane >> 4;
#pragma unroll
    for (int ct = 0; ct < 8; ++ct) {
        int col = ct * 16 + colL;
        float bv = bias[col];
#pragma unroll
        for (int reg = 0; reg < 4; ++reg) {
            int gr = row0 + rt * 16 + rq * 4 + reg;
            if (gr >= N) continue;
            Hout[(size_t)gr * 128 + col] = f2bf(tanhf(acc[ct][reg] + bv));
        }
    }
}

// out[N,32] = H_bf16[N,128] @ Wout^T + bout (fp32). BM=128.
__global__ __launch_bounds__(256) void mfma_gemm_out(
    const ushort_t* __restrict__ H, const ushort_t* __restrict__ Wb,
    const float* __restrict__ bias, float* __restrict__ C, int N) {
    __shared__ short As[128 * 128];  // 32 KB
    __shared__ short Ws[32 * 128];   // 8 KB
    const int tid = threadIdx.x;
    const int row0 = blockIdx.x * 128;
#pragma unroll
    for (int it = 0; it < 8; ++it) {
        int c = tid + 256 * it;
        int mm = c & 15, q = (c >> 4) & 3, ks = (c >> 6) & 3, rt = c >> 8;
        int gr = row0 + rt * 16 + mm;
        short8 v = {0, 0, 0, 0, 0, 0, 0, 0};
        if (gr < N) v = *(const short8*)(H + (size_t)gr * 128 + ks * 32 + q * 8);
        *(short8*)&As[c * 8] = v;
    }
#pragma unroll
    for (int it = 0; it < 2; ++it) {
        int c = tid + 256 * it;
        int mm = c & 15, q = (c >> 4) & 3, ks = (c >> 6) & 3, ct = c >> 8;
        *(short8*)&Ws[c * 8] =
            *(const short8*)(Wb + (ct * 16 + mm) * 128 + ks * 32 + q * 8);
    }
    __syncthreads();
    const int wv = tid >> 6, lane = tid & 63;
    const int rt0 = wv * 2;
    f32x4 acc[2][2];
#pragma unroll
    for (int r = 0; r < 2; ++r)
#pragma unroll
        for (int c = 0; c < 2; ++c) acc[r][c] = (f32x4){0.f, 0.f, 0.f, 0.f};
#pragma unroll
    for (int ks = 0; ks < 4; ++ks) {
        short8 a0 = *(const short8*)&As[(((rt0 + 0) * 4 + ks) * 64 + lane) * 8];
        short8 a1 = *(const short8*)&As[(((rt0 + 1) * 4 + ks) * 64 + lane) * 8];
#pragma unroll
        for (int ct = 0; ct < 2; ++ct) {
            short8 b = *(const short8*)&Ws[((ct * 4 + ks) * 64 + lane) * 8];
            acc[0][ct] = __builtin_amdgcn_mfma_f32_16x16x32_bf16(a0, b, acc[0][ct], 0, 0, 0);
            acc[1][ct] = __builtin_amdgcn_mfma_f32_16x16x32_bf16(a1, b, acc[1][ct], 0, 0, 0);
        }
    }
    const int colL = lane & 15, rq = lane >> 4;
#pragma unroll
    for (int r = 0; r < 2; ++r)
#pragma unroll
        for (int ct = 0; ct < 2; ++ct) {
            int col = ct * 16 + colL;
            float bv = bias[col];
#pragma unroll
            for (int reg = 0; reg < 4; ++reg) {
                int gr = row0 + (rt0 + r) * 16 + rq * 4 + reg;
                if (gr < N) C[(size_t)gr * 32 + col] = acc[r][ct][reg] + bv;
            }
        }
}

extern "C" void kernel_launch(void* const* d_in, const int* in_sizes, int n_in,
                              void* d_out, int out_size, void* d_ws, size_t ws_size,
                              hipStream_t stream) {
    const float* x   = (const float*)d_in[0];
    const int* ei    = (const int*)d_in[1];
    const float* ew  = (const float*)d_in[2];
    const float* Wm[3] = {(const float*)d_in[3], (const float*)d_in[6], (const float*)d_in[9]};
    const float* Wu[3] = {(const float*)d_in[4], (const float*)d_in[7], (const float*)d_in[10]};
    const float* bu[3] = {(const float*)d_in[5], (const float*)d_in[8], (const float*)d_in[11]};
    const float* Wout = (const float*)d_in[12];
    const float* bout = (const float*)d_in[13];
    float* out = (float*)d_out;

    const int N = in_sizes[0] / 128;
    const int E = in_sizes[2];
    const size_t NPAD = 50048;
    const int NB = (N + 127) / 128;      // 391 buckets
    const int TI = NB * TSTRIDE;         // tail ints

    ushort_t* xb    = (ushort_t*)d_ws;              // [N,128] bf16
    ushort_t* hA    = xb + NPAD * 128;
    ushort_t* hB    = hA + NPAD * 128;
    ushort_t* gbuf  = hB + NPAD * 128;
    ushort_t* wcat  = gbuf + NPAD * 128;            // 3*128*256 bf16
    ushort_t* woutb = wcat + 3 * 32768;             // 32*128 bf16
    int* flag       = (int*)(woutb + 4096);
    int* tails      = flag + 1;
    int* csrBase    = tails + TI;
    int* rowend     = csrBase + NB + 8;
    int* deg        = rowend + N;
    int* endp       = deg + N;
    uint2* staged   = (uint2*)(((uintptr_t)endp + 7) & ~(uintptr_t)7);
    uint_t* csr     = (uint_t*)(staged + (size_t)NB * CAPB);
    (void)ws_size;

    const int ZT = (TI + 255) / 256;                // 25
    const int WB = (3 * 32768 + 4096 + 255) / 256;  // 400
    const int XB = (N * 32 + 255) / 256;            // 6250
    const int gB = (E + EPB - 1) / EPB;             // 391 bin blocks
    const int gG = (N + 63) / 64;                   // 782
    const int gA = (N + 3) / 4;                     // 1 wave/node
    const int gO = (N + 127) / 128;                 // 391

    SetupArgs sa;
    sa.Wm0 = Wm[0]; sa.Wu0 = Wu[0];
    sa.Wm1 = Wm[1]; sa.Wu1 = Wu[1];
    sa.Wm2 = Wm[2]; sa.Wu2 = Wu[2];
    sa.Wout = Wout; sa.x = x; sa.ei = ei;
    sa.wcat = wcat; sa.woutb = woutb; sa.xb = xb;
    sa.tails = tails; sa.flag = flag;
    sa.N = N; sa.E = E; sa.TI = TI;
    sa.ZT = ZT; sa.WB = WB; sa.XB = XB;
    setup_kernel<<<ZT + 1 + WB + XB, 256, 0, stream>>>(sa);

    bin_kernel<<<gB, 256, 0, stream>>>(ei, ew, flag, tails, staged, E, NB);
    bucket_scan<<<1, 512, 0, stream>>>(tails, csrBase, NB);
    place_kernel<<<NB, 256, 0, stream>>>(staged, tails, csrBase, csr, rowend, deg, N);

    const ushort_t* hin[3] = {xb, hA, hB};
    ushort_t* hout[3] = {hA, hB, hA};
    for (int l = 0; l < 3; ++l) {
        aggregate_h<<<gA, 256, 0, stream>>>(csr, rowend, deg, hin[l], gbuf, N, 0);
        aggregate_h<<<gA, 256, 0, stream>>>(csr, rowend, deg, hin[l], gbuf, N, 64);
        fused_gemm<<<gG, 256, 0, stream>>>(gbuf, hin[l], wcat + (size_t)l * 32768,
                                           bu[l], hout[l], N);
    }
    mfma_gemm_out<<<gO, 256, 0, stream>>>(hA, woutb, bout, out, N);
}

// Round 10
// 314.410 us; speedup vs baseline: 1.1597x; 1.1597x over previous
//
#include <hip/hip_runtime.h>
#include <hip/hip_bf16.h>
#include <cstddef>

// ---------------------------------------------------------------------------
// 3-layer MPNN, N=50000, E=800000, D=128, OUT=32.
// R10: layer GEMM rewritten LDS-free (R9 evidence: MfmaUtil 2.2%, 50us --
// latency-bound on stage->barrier->MFMA). W pre-swizzled into MFMA B-frag
// order at setup; waves load a/b frags directly from global (L2-resident),
// no barriers. Aggregate reverted to R8 single-pass (2-pass L2 theory
// disproven). Bin keeps R9 LDS multi-split.
//   g = Sigma_in w*h[src]; h' = tanh([g|h]@[Wm;Wu]^T+bu); out = h3@Wout^T+b.
// CSR entry: (src:u16 | w:bf16<<16).
// B-frag layout (16x16x32 bf16, verified via R3-R9 LDS path): for (ct,ks):
//   lane=(kgroup<<4)|col16, elem j -> W[(ct*16+col16)*256 + ks*32+kgroup*8+j]
// stored flat at ((ct*8+ks)*64+lane)*8+j.
// ---------------------------------------------------------------------------

typedef __attribute__((ext_vector_type(8))) short short8;
typedef __attribute__((ext_vector_type(4))) float f32x4;
typedef unsigned short ushort_t;
typedef unsigned int uint_t;

#define CAPB 4096           // staged entries per bucket (max bucket ~2.3k)
#define TSTRIDE 16          // tails counter stride in ints (64B line each)
#define EPB 2048            // edges per bin block

__device__ inline ushort_t f2bf(float f) {  // round-to-nearest-even
    uint_t u = __float_as_uint(f);
    uint_t r = u + 0x7FFFu + ((u >> 16) & 1u);
    return (ushort_t)(r >> 16);
}
__device__ inline float bf_lo(uint_t u) { return __uint_as_float(u << 16); }
__device__ inline float bf_hi(uint_t u) { return __uint_as_float(u & 0xFFFF0000u); }
__device__ inline uint_t packbf(float a, float b) {
    return (uint_t)f2bf(a) | ((uint_t)f2bf(b) << 16);
}

// flag=1 -> int32 [2][E]; flag=0 -> int64 [2][E] (vectorized low-word read)
__device__ inline int get_dst(const int* __restrict__ ei, int e, int E, int f) {
    if (f) return ei[E + e];
    return ((const int2*)ei)[(size_t)E + e].x;
}
__device__ inline int get_src(const int* __restrict__ ei, int e, int E, int f) {
    if (f) return ei[e];
    return ((const int2*)ei)[e].x;
}

// ---------------------------------------------------------------------------
// Fused setup: zero tails | detect idx layout | swizzled bf16 weights |
// x -> bf16.
// wswz[l]: flat ((ct*8+ks)*64+lane)*8+j <- Wcat[(ct*16+(lane&15))][ks*32+
//   (lane>>4)*8+j]  (Wcat = [Wm | Wu], K=256)
// woswz:   flat ((ct*4+ks)*64+lane)*8+j <- Wout[(ct*16+(lane&15))][ks*32+
//   (lane>>4)*8+j]  (K=128, ct<2)
// ---------------------------------------------------------------------------
struct SetupArgs {
    const float* Wm0; const float* Wu0;
    const float* Wm1; const float* Wu1;
    const float* Wm2; const float* Wu2;
    const float* Wout;
    const float* x; const int* ei;
    ushort_t* wswz;    // 3 * 32768
    ushort_t* woswz;   // 4096
    ushort_t* xb;      // N*128
    int* tails;
    int* flag;
    int N, E, TI;
    int ZT, WB, XB;
};
__global__ __launch_bounds__(256) void setup_kernel(SetupArgs a) {
    int bx = blockIdx.x, t = threadIdx.x;
    if (bx < a.ZT) {
        int i = bx * 256 + t;
        if (i < a.TI) a.tails[i] = 0;
        return;
    }
    bx -= a.ZT;
    if (bx == 0) {
        __shared__ int any;
        if (t == 0) any = 0;
        __syncthreads();
        int n = a.E < 2048 ? a.E : 2048;
        for (int i = t; i < n; i += 256)
            if (a.ei[2 * i + 1] != 0) any = 1;
        __syncthreads();
        if (t == 0) a.flag[0] = any;
        return;
    }
    bx -= 1;
    if (bx < a.WB) {
        int i = bx * 256 + t;
        if (i < 3 * 32768) {
            int l = i >> 15, r2 = i & 32767;
            int ct = r2 >> 12, ks = (r2 >> 9) & 7, lane = (r2 >> 3) & 63, j = r2 & 7;
            int col = ct * 16 + (lane & 15);
            int k = ks * 32 + (lane >> 4) * 8 + j;
            const float* Wm = l == 0 ? a.Wm0 : (l == 1 ? a.Wm1 : a.Wm2);
            const float* Wu = l == 0 ? a.Wu0 : (l == 1 ? a.Wu1 : a.Wu2);
            float v = k < 128 ? Wm[col * 128 + k] : Wu[col * 128 + (k - 128)];
            a.wswz[(size_t)l * 32768 + r2] = f2bf(v);
        } else if (i < 3 * 32768 + 4096) {
            int r2 = i - 3 * 32768;
            int ct = r2 >> 11, ks = (r2 >> 9) & 3, lane = (r2 >> 3) & 63, j = r2 & 7;
            int col = ct * 16 + (lane & 15);
            int k = ks * 32 + (lane >> 4) * 8 + j;
            a.woswz[r2] = f2bf(a.Wout[col * 128 + k]);
        }
        return;
    }
    bx -= a.WB;
    {
        int j = bx * 256 + t;
        if (j < a.N * 32) {
            float4 v = *(const float4*)(a.x + (size_t)j * 4);
            uint2 o;
            o.x = packbf(v.x, v.y);
            o.y = packbf(v.z, v.w);
            *(uint2*)(a.xb + (size_t)j * 4) = o;
        }
    }
}

// ---------------------------------------------------------------------------
// Phase A: LDS multi-split binning (one global atomic per (block,bucket)).
// ---------------------------------------------------------------------------
__global__ __launch_bounds__(256) void bin_kernel(
    const int* __restrict__ ei, const float* __restrict__ ew,
    const int* __restrict__ flag, int* __restrict__ tails,
    uint2* __restrict__ staged, int E, int NB) {
    __shared__ uint2 ent[EPB];           // 16 KB
    __shared__ int cnt[512], cur[512], runbase[512];
    const int tid = threadIdx.x;
    const int e0 = blockIdx.x * EPB;
    const int nE = (E - e0) < EPB ? (E - e0) : EPB;
    const int f = flag[0];
    for (int b = tid; b < 512; b += 256) { cnt[b] = 0; cur[b] = 0; }
    __syncthreads();
    for (int i = tid; i < nE; i += 256) {
        int e = e0 + i;
        int s = get_src(ei, e, E, f);
        int d = get_dst(ei, e, E, f);
        uint2 v;
        v.x = (uint_t)s | ((uint_t)f2bf(ew[e]) << 16);
        v.y = (uint_t)d;
        ent[i] = v;
        atomicAdd(&cnt[d >> 7], 1);      // LDS atomic
    }
    __syncthreads();
    for (int b = tid; b < NB; b += 256) {
        int c = cnt[b];
        runbase[b] = c ? atomicAdd(&tails[b * TSTRIDE], c) : 0;
    }
    __syncthreads();
    for (int i = tid; i < nE; i += 256) {
        uint2 v = ent[i];
        int d = (int)v.y;
        int b = d >> 7;
        int lp = atomicAdd(&cur[b], 1);  // LDS atomic
        int gp = runbase[b] + lp;
        if (gp < CAPB) {
            uint2 o;
            o.x = v.x;
            o.y = (uint_t)(d & 127);
            staged[(size_t)b * CAPB + gp] = o;
        }
    }
}

// exclusive scan of per-bucket totals -> csrBase[NB]. NB<=512, one block.
__global__ __launch_bounds__(512) void bucket_scan(
    const int* __restrict__ tails, int* __restrict__ csrBase, int NB) {
    __shared__ int sm[512];
    int t = threadIdx.x;
    int s = 0;
    if (t < NB) {
        int c = tails[t * TSTRIDE];
        s = c < CAPB ? c : CAPB;
    }
    sm[t] = s;
    __syncthreads();
    for (int o = 1; o < 512; o <<= 1) {
        int v = t >= o ? sm[t - o] : 0;
        __syncthreads();
        sm[t] += v;
        __syncthreads();
    }
    if (t < NB) csrBase[t] = sm[t] - s;
}

// ---------------------------------------------------------------------------
// Phase B: one block per bucket -> LDS hist/scan/place -> coalesced flush.
// ---------------------------------------------------------------------------
__global__ __launch_bounds__(256) void place_kernel(
    const uint2* __restrict__ staged, const int* __restrict__ tails,
    const int* __restrict__ csrBase, uint_t* __restrict__ csr,
    int* __restrict__ rowend, int* __restrict__ deg, int N) {
    __shared__ int cnt[128], cur[128], excl[128], sm[256];
    __shared__ uint_t outb[CAPB];        // 16 KB
    const int b = blockIdx.x, tid = threadIdx.x;
    const int node0 = b << 7;
    const int base = csrBase[b];
    int tot = tails[b * TSTRIDE];
    tot = tot < CAPB ? tot : CAPB;
    if (tid < 128) cnt[tid] = 0;
    __syncthreads();
    const uint2* sp = staged + ((size_t)b * CAPB);
    for (int i = tid; i < tot; i += 256) atomicAdd(&cnt[sp[i].y], 1);
    __syncthreads();
    int c0 = tid < 128 ? cnt[tid] : 0;
    sm[tid] = c0;
    __syncthreads();
    for (int o = 1; o < 256; o <<= 1) {
        int v = tid >= o ? sm[tid - o] : 0;
        __syncthreads();
        sm[tid] += v;
        __syncthreads();
    }
    if (tid < 128) {
        excl[tid] = sm[tid] - c0;
        cur[tid] = 0;
    }
    __syncthreads();
    for (int i = tid; i < tot; i += 256) {
        uint2 e = sp[i];
        int pos = excl[e.y] + atomicAdd(&cur[e.y], 1);
        outb[pos] = e.x;
    }
    __syncthreads();
    for (int i = tid; i < tot; i += 256) csr[base + i] = outb[i];
    if (tid < 128 && node0 + tid < N) {
        deg[node0 + tid] = c0;
        rowend[node0 + tid] = base + excl[tid] + c0;
    }
}

// ---------------------------------------------------------------------------
// Aggregate: g[d] = Sigma_{in(d)} w*h[src]. One 64-lane wave per node.
// lane = slot(0..7)*8 + f8(0..7); lane owns 16 feats via 2x uint4 loads.
// ---------------------------------------------------------------------------
__global__ __launch_bounds__(256) void aggregate_g(
    const uint_t* __restrict__ csr, const int* __restrict__ rowend,
    const int* __restrict__ deg, const ushort_t* __restrict__ h,
    ushort_t* __restrict__ g, int N) {
    int node = (blockIdx.x * 256 + threadIdx.x) >> 6;
    if (node >= N) return;
    int lane = threadIdx.x & 63;
    int slot = lane >> 3, f8 = lane & 7;
    int end = rowend[node];
    int beg = end - deg[node];
    float s[16];
#pragma unroll
    for (int k = 0; k < 16; ++k) s[k] = 0.f;
    for (int j = beg + slot; j < end; j += 8) {
        uint_t p = csr[j];
        float w = bf_hi(p);
        const ushort_t* row = h + (size_t)(p & 0xFFFFu) * 128 + f8 * 16;
        uint4 v0 = *(const uint4*)(row);
        uint4 v1 = *(const uint4*)(row + 8);
        s[0] += w * bf_lo(v0.x);  s[1] += w * bf_hi(v0.x);
        s[2] += w * bf_lo(v0.y);  s[3] += w * bf_hi(v0.y);
        s[4] += w * bf_lo(v0.z);  s[5] += w * bf_hi(v0.z);
        s[6] += w * bf_lo(v0.w);  s[7] += w * bf_hi(v0.w);
        s[8] += w * bf_lo(v1.x);  s[9] += w * bf_hi(v1.x);
        s[10] += w * bf_lo(v1.y); s[11] += w * bf_hi(v1.y);
        s[12] += w * bf_lo(v1.z); s[13] += w * bf_hi(v1.z);
        s[14] += w * bf_lo(v1.w); s[15] += w * bf_hi(v1.w);
    }
#pragma unroll
    for (int k = 0; k < 16; ++k) s[k] += __shfl_xor(s[k], 8, 64);
#pragma unroll
    for (int k = 0; k < 16; ++k) s[k] += __shfl_xor(s[k], 16, 64);
#pragma unroll
    for (int k = 0; k < 16; ++k) s[k] += __shfl_xor(s[k], 32, 64);
    if (slot == 0) {
        uint4 o0, o1;
        o0.x = packbf(s[0], s[1]);   o0.y = packbf(s[2], s[3]);
        o0.z = packbf(s[4], s[5]);   o0.w = packbf(s[6], s[7]);
        o1.x = packbf(s[8], s[9]);   o1.y = packbf(s[10], s[11]);
        o1.z = packbf(s[12], s[13]); o1.w = packbf(s[14], s[15]);
        ushort_t* gp = g + (size_t)node * 128 + f8 * 16;
        *(uint4*)(gp) = o0;
        *(uint4*)(gp + 8) = o1;
    }
}

// ---------------------------------------------------------------------------
// LDS-free layer GEMM: Hout[N,128] = tanh([G|H][N,256] @ Wswz + bu).
// Block 256 = 4 waves; wave owns 16 rows (BM=64/block), all 128 cols.
// a-frag: lane reads A[row0+(lane&15)][*]; b-frag: coalesced 16B from wswz.
// No LDS, no barriers. Buffers padded to NPAD rows -> no load guards.
// ---------------------------------------------------------------------------
__global__ __launch_bounds__(256) void fused_gemm(
    const ushort_t* __restrict__ G, const ushort_t* __restrict__ H,
    const ushort_t* __restrict__ Wswz, const float* __restrict__ bias,
    ushort_t* __restrict__ Hout, int N) {
    const int tid = threadIdx.x;
    const int lane = tid & 63;
    const int row0 = blockIdx.x * 64 + (tid >> 6) * 16;
    const int m = lane & 15, kg = lane >> 4;

    const ushort_t* ag = G + (size_t)(row0 + m) * 128 + kg * 8;
    const ushort_t* ah = H + (size_t)(row0 + m) * 128 + kg * 8;

    f32x4 acc[8];
#pragma unroll
    for (int ct = 0; ct < 8; ++ct) acc[ct] = (f32x4){0.f, 0.f, 0.f, 0.f};

#pragma unroll
    for (int ksp = 0; ksp < 8; ++ksp) {
        const ushort_t* base = (ksp < 4) ? ag : ah;
        short8 a = *(const short8*)(base + (ksp & 3) * 32);
#pragma unroll
        for (int ct = 0; ct < 8; ++ct) {
            short8 b = *(const short8*)(Wswz + ((ct * 8 + ksp) * 64 + lane) * 8);
            acc[ct] = __builtin_amdgcn_mfma_f32_16x16x32_bf16(a, b, acc[ct], 0, 0, 0);
        }
    }
    const int colL = lane & 15, rq = lane >> 4;
#pragma unroll
    for (int ct = 0; ct < 8; ++ct) {
        int col = ct * 16 + colL;
        float bv = bias[col];
#pragma unroll
        for (int reg = 0; reg < 4; ++reg) {
            int gr = row0 + rq * 4 + reg;
            if (gr < N) Hout[(size_t)gr * 128 + col] = f2bf(tanhf(acc[ct][reg] + bv));
        }
    }
}

// LDS-free output GEMM: out[N,32] = H[N,128] @ Woswz + bout (fp32).
__global__ __launch_bounds__(256) void mfma_gemm_out(
    const ushort_t* __restrict__ H, const ushort_t* __restrict__ Wswz,
    const float* __restrict__ bias, float* __restrict__ C, int N) {
    const int tid = threadIdx.x;
    const int lane = tid & 63;
    const int row0 = blockIdx.x * 64 + (tid >> 6) * 16;
    const int m = lane & 15;
    const ushort_t* ah = H + (size_t)(row0 + m) * 128 + (lane >> 4) * 8;

    f32x4 acc[2];
#pragma unroll
    for (int ct = 0; ct < 2; ++ct) acc[ct] = (f32x4){0.f, 0.f, 0.f, 0.f};
#pragma unroll
    for (int ks = 0; ks < 4; ++ks) {
        short8 a = *(const short8*)(ah + ks * 32);
#pragma unroll
        for (int ct = 0; ct < 2; ++ct) {
            short8 b = *(const short8*)(Wswz + ((ct * 4 + ks) * 64 + lane) * 8);
            acc[ct] = __builtin_amdgcn_mfma_f32_16x16x32_bf16(a, b, acc[ct], 0, 0, 0);
        }
    }
    const int colL = lane & 15, rq = lane >> 4;
#pragma unroll
    for (int ct = 0; ct < 2; ++ct) {
        int col = ct * 16 + colL;
        float bv = bias[col];
#pragma unroll
        for (int reg = 0; reg < 4; ++reg) {
            int gr = row0 + rq * 4 + reg;
            if (gr < N) C[(size_t)gr * 32 + col] = acc[ct][reg] + bv;
        }
    }
}

extern "C" void kernel_launch(void* const* d_in, const int* in_sizes, int n_in,
                              void* d_out, int out_size, void* d_ws, size_t ws_size,
                              hipStream_t stream) {
    const float* x   = (const float*)d_in[0];
    const int* ei    = (const int*)d_in[1];
    const float* ew  = (const float*)d_in[2];
    const float* Wm[3] = {(const float*)d_in[3], (const float*)d_in[6], (const float*)d_in[9]};
    const float* Wu[3] = {(const float*)d_in[4], (const float*)d_in[7], (const float*)d_in[10]};
    const float* bu[3] = {(const float*)d_in[5], (const float*)d_in[8], (const float*)d_in[11]};
    const float* Wout = (const float*)d_in[12];
    const float* bout = (const float*)d_in[13];
    float* out = (float*)d_out;

    const int N = in_sizes[0] / 128;
    const int E = in_sizes[2];
    const size_t NPAD = 50048;
    const int NB = (N + 127) / 128;      // 391 buckets
    const int TI = NB * TSTRIDE;

    ushort_t* xb    = (ushort_t*)d_ws;              // [NPAD,128] bf16
    ushort_t* hA    = xb + NPAD * 128;
    ushort_t* hB    = hA + NPAD * 128;
    ushort_t* gbuf  = hB + NPAD * 128;
    ushort_t* wswz  = gbuf + NPAD * 128;            // 3*32768 bf16
    ushort_t* woswz = wswz + 3 * 32768;             // 4096 bf16
    int* flag       = (int*)(woswz + 4096);
    int* tails      = flag + 1;
    int* csrBase    = tails + TI;
    int* rowend     = csrBase + NB + 8;
    int* deg        = rowend + N;
    int* endp       = deg + N;
    uint2* staged   = (uint2*)(((uintptr_t)endp + 7) & ~(uintptr_t)7);
    uint_t* csr     = (uint_t*)(staged + (size_t)NB * CAPB);
    (void)ws_size;

    const int ZT = (TI + 255) / 256;
    const int WB = (3 * 32768 + 4096 + 255) / 256;  // 400
    const int XB = (N * 32 + 255) / 256;            // 6250
    const int gB = (E + EPB - 1) / EPB;             // 391
    const int gG = (N + 63) / 64;                   // 782
    const int gA = (N + 3) / 4;                     // 12500
    const int gO = (N + 63) / 64;                   // 782

    SetupArgs sa;
    sa.Wm0 = Wm[0]; sa.Wu0 = Wu[0];
    sa.Wm1 = Wm[1]; sa.Wu1 = Wu[1];
    sa.Wm2 = Wm[2]; sa.Wu2 = Wu[2];
    sa.Wout = Wout; sa.x = x; sa.ei = ei;
    sa.wswz = wswz; sa.woswz = woswz; sa.xb = xb;
    sa.tails = tails; sa.flag = flag;
    sa.N = N; sa.E = E; sa.TI = TI;
    sa.ZT = ZT; sa.WB = WB; sa.XB = XB;
    setup_kernel<<<ZT + 1 + WB + XB, 256, 0, stream>>>(sa);

    bin_kernel<<<gB, 256, 0, stream>>>(ei, ew, flag, tails, staged, E, NB);
    bucket_scan<<<1, 512, 0, stream>>>(tails, csrBase, NB);
    place_kernel<<<NB, 256, 0, stream>>>(staged, tails, csrBase, csr, rowend, deg, N);

    const ushort_t* hin[3] = {xb, hA, hB};
    ushort_t* hout[3] = {hA, hB, hA};
    for (int l = 0; l < 3; ++l) {
        aggregate_g<<<gA, 256, 0, stream>>>(csr, rowend, deg, hin[l], gbuf, N);
        fused_gemm<<<gG, 256, 0, stream>>>(gbuf, hin[l], wswz + (size_t)l * 32768,
                                           bu[l], hout[l], N);
    }
    mfma_gemm_out<<<gO, 256, 0, stream>>>(hA, woswz, bout, out, N);
}

// Round 12
// 310.747 us; speedup vs baseline: 1.1734x; 1.0118x over previous
//
#include <hip/hip_runtime.h>
#include <hip/hip_bf16.h>
#include <cstddef>

// ---------------------------------------------------------------------------
// 3-layer MPNN, N=50000, E=800000, D=128, OUT=32.
// R12 (= R11 + compile fix): 256-node buckets (halves bin's contended
// reserve atomics: 196x196 vs 391x391), bucket_scan eliminated (place
// self-allocates its CSR region via one global atomic cursor), rowdeg packed
// int2 (one header load in aggregate). GEMMs stay LDS-free w/ preswizzled W
// (R10); aggregate stays 8-slot single-pass (R8/R10).
//   g = Sigma_in w*h[src]; h' = tanh([g|h]@[Wm;Wu]^T+bu); out = h3@Wout^T+b.
// CSR entry: (src:u16 | w:bf16<<16).
// ---------------------------------------------------------------------------

typedef __attribute__((ext_vector_type(8))) short short8;
typedef __attribute__((ext_vector_type(4))) float f32x4;
typedef unsigned short ushort_t;
typedef unsigned int uint_t;

#define BSH 8               // bucket shift: 256 nodes per bucket
#define BSZ 256             // nodes per bucket
#define CAPB 6144           // staged entries per bucket (mean 4096, >30 sigma)
#define TSTRIDE 16          // tails counter stride in ints (64B line each)
#define EPB 2048            // edges per bin block

__device__ inline ushort_t f2bf(float f) {  // round-to-nearest-even
    uint_t u = __float_as_uint(f);
    uint_t r = u + 0x7FFFu + ((u >> 16) & 1u);
    return (ushort_t)(r >> 16);
}
__device__ inline float bf_lo(uint_t u) { return __uint_as_float(u << 16); }
__device__ inline float bf_hi(uint_t u) { return __uint_as_float(u & 0xFFFF0000u); }
__device__ inline uint_t packbf(float a, float b) {
    return (uint_t)f2bf(a) | ((uint_t)f2bf(b) << 16);
}

// flag=1 -> int32 [2][E]; flag=0 -> int64 [2][E] (vectorized low-word read)
__device__ inline int get_dst(const int* __restrict__ ei, int e, int E, int f) {
    if (f) return ei[E + e];
    return ((const int2*)ei)[(size_t)E + e].x;
}
__device__ inline int get_src(const int* __restrict__ ei, int e, int E, int f) {
    if (f) return ei[e];
    return ((const int2*)ei)[e].x;
}

// ---------------------------------------------------------------------------
// Fused setup: zero tails+cursor | detect idx layout | swizzled bf16 weights
// | x -> bf16.
// wswz[l]: flat ((ct*8+ks)*64+lane)*8+j <- Wcat[(ct*16+(lane&15))][ks*32+
//   (lane>>4)*8+j]  (Wcat = [Wm | Wu], K=256)
// woswz:   flat ((ct*4+ks)*64+lane)*8+j <- Wout[...]  (K=128, ct<2)
// ---------------------------------------------------------------------------
struct SetupArgs {
    const float* Wm0; const float* Wu0;
    const float* Wm1; const float* Wu1;
    const float* Wm2; const float* Wu2;
    const float* Wout;
    const float* x; const int* ei;
    ushort_t* wswz;    // 3 * 32768
    ushort_t* woswz;   // 4096
    ushort_t* xb;      // N*128
    int* tails;        // NB*TSTRIDE + cursor (zeroed together)
    int* flag;
    int N, E, TI;
    int ZT, WB, XB;
};
__global__ __launch_bounds__(256) void setup_kernel(SetupArgs a) {
    int bx = blockIdx.x, t = threadIdx.x;
    if (bx < a.ZT) {
        int i = bx * 256 + t;
        if (i < a.TI) a.tails[i] = 0;
        return;
    }
    bx -= a.ZT;
    if (bx == 0) {
        __shared__ int any;
        if (t == 0) any = 0;
        __syncthreads();
        int n = a.E < 2048 ? a.E : 2048;
        for (int i = t; i < n; i += 256)
            if (a.ei[2 * i + 1] != 0) any = 1;
        __syncthreads();
        if (t == 0) a.flag[0] = any;
        return;
    }
    bx -= 1;
    if (bx < a.WB) {
        int i = bx * 256 + t;
        if (i < 3 * 32768) {
            int l = i >> 15, r2 = i & 32767;
            int ct = r2 >> 12, ks = (r2 >> 9) & 7, lane = (r2 >> 3) & 63, j = r2 & 7;
            int col = ct * 16 + (lane & 15);
            int k = ks * 32 + (lane >> 4) * 8 + j;
            const float* Wm = l == 0 ? a.Wm0 : (l == 1 ? a.Wm1 : a.Wm2);
            const float* Wu = l == 0 ? a.Wu0 : (l == 1 ? a.Wu1 : a.Wu2);
            float v = k < 128 ? Wm[col * 128 + k] : Wu[col * 128 + (k - 128)];
            a.wswz[(size_t)l * 32768 + r2] = f2bf(v);
        } else if (i < 3 * 32768 + 4096) {
            int r2 = i - 3 * 32768;
            int ct = r2 >> 11, ks = (r2 >> 9) & 3, lane = (r2 >> 3) & 63, j = r2 & 7;
            int col = ct * 16 + (lane & 15);
            int k = ks * 32 + (lane >> 4) * 8 + j;
            a.woswz[r2] = f2bf(a.Wout[col * 128 + k]);
        }
        return;
    }
    bx -= a.WB;
    {
        int j = bx * 256 + t;
        if (j < a.N * 32) {
            float4 v = *(const float4*)(a.x + (size_t)j * 4);
            uint2 o;
            o.x = packbf(v.x, v.y);
            o.y = packbf(v.z, v.w);
            *(uint2*)(a.xb + (size_t)j * 4) = o;
        }
    }
}

// ---------------------------------------------------------------------------
// Phase A: LDS multi-split binning (one global atomic per (block,bucket)).
// bucket = dst>>8 (256 nodes). ~77k reserve atomics total.
// ---------------------------------------------------------------------------
__global__ __launch_bounds__(256) void bin_kernel(
    const int* __restrict__ ei, const float* __restrict__ ew,
    const int* __restrict__ flag, int* __restrict__ tails,
    uint2* __restrict__ staged, int E, int NB) {
    __shared__ uint2 ent[EPB];           // 16 KB
    __shared__ int cnt[256], cur[256], runbase[256];
    const int tid = threadIdx.x;
    const int e0 = blockIdx.x * EPB;
    const int nE = (E - e0) < EPB ? (E - e0) : EPB;
    const int f = flag[0];
    cnt[tid] = 0;
    cur[tid] = 0;
    __syncthreads();
    for (int i = tid; i < nE; i += 256) {
        int e = e0 + i;
        int s = get_src(ei, e, E, f);
        int d = get_dst(ei, e, E, f);
        uint2 v;
        v.x = (uint_t)s | ((uint_t)f2bf(ew[e]) << 16);
        v.y = (uint_t)d;
        ent[i] = v;
        atomicAdd(&cnt[d >> BSH], 1);    // LDS atomic
    }
    __syncthreads();
    if (tid < NB) {
        int c = cnt[tid];
        runbase[tid] = c ? atomicAdd(&tails[tid * TSTRIDE], c) : 0;
    }
    __syncthreads();
    for (int i = tid; i < nE; i += 256) {
        uint2 v = ent[i];
        int d = (int)v.y;
        int b = d >> BSH;
        int lp = atomicAdd(&cur[b], 1);  // LDS atomic
        int gp = runbase[b] + lp;
        if (gp < CAPB) {
            uint2 o;
            o.x = v.x;
            o.y = (uint_t)(d & (BSZ - 1));
            staged[(size_t)b * CAPB + gp] = o;
        }
    }
}

// ---------------------------------------------------------------------------
// Phase B: one block per bucket. Self-allocates the bucket's contiguous CSR
// region via a global cursor (bucket order arbitrary -- only rowspans
// matter). LDS hist (256 nodes) -> LDS excl scan -> LDS image -> coalesced
// flush. Writes rowdeg[node] = int2{beg, end}.
// ---------------------------------------------------------------------------
__global__ __launch_bounds__(256) void place_kernel(
    const uint2* __restrict__ staged, const int* __restrict__ tails,
    int* __restrict__ cursor, uint_t* __restrict__ csr,
    int2* __restrict__ rowdeg, int N) {
    __shared__ int cnt[256], cur[256], excl[256], sm[256];
    __shared__ int baseSh;
    __shared__ uint_t outb[CAPB];        // 24 KB
    const int b = blockIdx.x, tid = threadIdx.x;
    const int node0 = b << BSH;
    int tot = tails[b * TSTRIDE];
    tot = tot < CAPB ? tot : CAPB;
    cnt[tid] = 0;
    __syncthreads();
    const uint2* sp = staged + ((size_t)b * CAPB);
    for (int i = tid; i < tot; i += 256) atomicAdd(&cnt[sp[i].y], 1);
    __syncthreads();
    int c0 = cnt[tid];
    sm[tid] = c0;
    __syncthreads();
    for (int o = 1; o < 256; o <<= 1) {
        int v = tid >= o ? sm[tid - o] : 0;
        __syncthreads();
        sm[tid] += v;
        __syncthreads();
    }
    if (tid == 255) baseSh = atomicAdd(cursor, sm[255]);
    excl[tid] = sm[tid] - c0;
    cur[tid] = 0;
    __syncthreads();
    const int base = baseSh;
    for (int i = tid; i < tot; i += 256) {
        uint2 e = sp[i];
        int pos = excl[e.y] + atomicAdd(&cur[e.y], 1);
        outb[pos] = e.x;
    }
    __syncthreads();
    for (int i = tid; i < tot; i += 256) csr[base + i] = outb[i];
    if (node0 + tid < N) {
        int2 be;
        be.x = base + excl[tid];
        be.y = base + excl[tid] + c0;
        rowdeg[node0 + tid] = be;
    }
}

// ---------------------------------------------------------------------------
// Aggregate: g[d] = Sigma_{in(d)} w*h[src]. One 64-lane wave per node.
// lane = slot(0..7)*8 + f8(0..7); lane owns 16 feats via 2x uint4 loads.
// ---------------------------------------------------------------------------
__global__ __launch_bounds__(256) void aggregate_g(
    const uint_t* __restrict__ csr, const int2* __restrict__ rowdeg,
    const ushort_t* __restrict__ h, ushort_t* __restrict__ g, int N) {
    int node = (blockIdx.x * 256 + threadIdx.x) >> 6;
    if (node >= N) return;
    int lane = threadIdx.x & 63;
    int slot = lane >> 3, f8 = lane & 7;
    int2 be = rowdeg[node];
    int beg = be.x, end = be.y;
    float s[16];
#pragma unroll
    for (int k = 0; k < 16; ++k) s[k] = 0.f;
    for (int j = beg + slot; j < end; j += 8) {
        uint_t p = csr[j];
        float w = bf_hi(p);
        const ushort_t* row = h + (size_t)(p & 0xFFFFu) * 128 + f8 * 16;
        uint4 v0 = *(const uint4*)(row);
        uint4 v1 = *(const uint4*)(row + 8);
        s[0] += w * bf_lo(v0.x);  s[1] += w * bf_hi(v0.x);
        s[2] += w * bf_lo(v0.y);  s[3] += w * bf_hi(v0.y);
        s[4] += w * bf_lo(v0.z);  s[5] += w * bf_hi(v0.z);
        s[6] += w * bf_lo(v0.w);  s[7] += w * bf_hi(v0.w);
        s[8] += w * bf_lo(v1.x);  s[9] += w * bf_hi(v1.x);
        s[10] += w * bf_lo(v1.y); s[11] += w * bf_hi(v1.y);
        s[12] += w * bf_lo(v1.z); s[13] += w * bf_hi(v1.z);
        s[14] += w * bf_lo(v1.w); s[15] += w * bf_hi(v1.w);
    }
#pragma unroll
    for (int k = 0; k < 16; ++k) s[k] += __shfl_xor(s[k], 8, 64);
#pragma unroll
    for (int k = 0; k < 16; ++k) s[k] += __shfl_xor(s[k], 16, 64);
#pragma unroll
    for (int k = 0; k < 16; ++k) s[k] += __shfl_xor(s[k], 32, 64);
    if (slot == 0) {
        uint4 o0, o1;
        o0.x = packbf(s[0], s[1]);   o0.y = packbf(s[2], s[3]);
        o0.z = packbf(s[4], s[5]);   o0.w = packbf(s[6], s[7]);
        o1.x = packbf(s[8], s[9]);   o1.y = packbf(s[10], s[11]);
        o1.z = packbf(s[12], s[13]); o1.w = packbf(s[14], s[15]);
        ushort_t* gp = g + (size_t)node * 128 + f8 * 16;
        *(uint4*)(gp) = o0;
        *(uint4*)(gp + 8) = o1;
    }
}

// ---------------------------------------------------------------------------
// LDS-free layer GEMM: Hout[N,128] = tanh([G|H][N,256] @ Wswz + bu).
// Block 256 = 4 waves; wave owns 16 rows, all 128 cols. No LDS, no barriers.
// ---------------------------------------------------------------------------
__global__ __launch_bounds__(256) void fused_gemm(
    const ushort_t* __restrict__ G, const ushort_t* __restrict__ H,
    const ushort_t* __restrict__ Wswz, const float* __restrict__ bias,
    ushort_t* __restrict__ Hout, int N) {
    const int tid = threadIdx.x;
    const int lane = tid & 63;
    const int row0 = blockIdx.x * 64 + (tid >> 6) * 16;
    const int m = lane & 15, kg = lane >> 4;

    const ushort_t* ag = G + (size_t)(row0 + m) * 128 + kg * 8;
    const ushort_t* ah = H + (size_t)(row0 + m) * 128 + kg * 8;

    f32x4 acc[8];
#pragma unroll
    for (int ct = 0; ct < 8; ++ct) acc[ct] = (f32x4){0.f, 0.f, 0.f, 0.f};

#pragma unroll
    for (int ksp = 0; ksp < 8; ++ksp) {
        const ushort_t* base = (ksp < 4) ? ag : ah;
        short8 a = *(const short8*)(base + (ksp & 3) * 32);
#pragma unroll
        for (int ct = 0; ct < 8; ++ct) {
            short8 b = *(const short8*)(Wswz + ((ct * 8 + ksp) * 64 + lane) * 8);
            acc[ct] = __builtin_amdgcn_mfma_f32_16x16x32_bf16(a, b, acc[ct], 0, 0, 0);
        }
    }
    const int colL = lane & 15, rq = lane >> 4;
#pragma unroll
    for (int ct = 0; ct < 8; ++ct) {
        int col = ct * 16 + colL;
        float bv = bias[col];
#pragma unroll
        for (int reg = 0; reg < 4; ++reg) {
            int gr = row0 + rq * 4 + reg;
            if (gr < N) Hout[(size_t)gr * 128 + col] = f2bf(tanhf(acc[ct][reg] + bv));
        }
    }
}

// LDS-free output GEMM: out[N,32] = H[N,128] @ Woswz + bout (fp32).
__global__ __launch_bounds__(256) void mfma_gemm_out(
    const ushort_t* __restrict__ H, const ushort_t* __restrict__ Wswz,
    const float* __restrict__ bias, float* __restrict__ C, int N) {
    const int tid = threadIdx.x;
    const int lane = tid & 63;
    const int row0 = blockIdx.x * 64 + (tid >> 6) * 16;
    const int m = lane & 15;
    const ushort_t* ah = H + (size_t)(row0 + m) * 128 + (lane >> 4) * 8;

    f32x4 acc[2];
#pragma unroll
    for (int ct = 0; ct < 2; ++ct) acc[ct] = (f32x4){0.f, 0.f, 0.f, 0.f};
#pragma unroll
    for (int ks = 0; ks < 4; ++ks) {
        short8 a = *(const short8*)(ah + ks * 32);
#pragma unroll
        for (int ct = 0; ct < 2; ++ct) {
            short8 b = *(const short8*)(Wswz + ((ct * 4 + ks) * 64 + lane) * 8);
            acc[ct] = __builtin_amdgcn_mfma_f32_16x16x32_bf16(a, b, acc[ct], 0, 0, 0);
        }
    }
    const int colL = lane & 15, rq = lane >> 4;
#pragma unroll
    for (int ct = 0; ct < 2; ++ct) {
        int col = ct * 16 + colL;
        float bv = bias[col];
#pragma unroll
        for (int reg = 0; reg < 4; ++reg) {
            int gr = row0 + rq * 4 + reg;
            if (gr < N) C[(size_t)gr * 32 + col] = acc[ct][reg] + bv;
        }
    }
}

extern "C" void kernel_launch(void* const* d_in, const int* in_sizes, int n_in,
                              void* d_out, int out_size, void* d_ws, size_t ws_size,
                              hipStream_t stream) {
    const float* x   = (const float*)d_in[0];
    const int* ei    = (const int*)d_in[1];
    const float* ew  = (const float*)d_in[2];
    const float* Wm[3] = {(const float*)d_in[3], (const float*)d_in[6], (const float*)d_in[9]};
    const float* Wu[3] = {(const float*)d_in[4], (const float*)d_in[7], (const float*)d_in[10]};
    const float* bu[3] = {(const float*)d_in[5], (const float*)d_in[8], (const float*)d_in[11]};
    const float* Wout = (const float*)d_in[12];
    const float* bout = (const float*)d_in[13];
    float* out = (float*)d_out;

    const int N = in_sizes[0] / 128;
    const int E = in_sizes[2];
    const size_t NPAD = 50048;
    const int NB = (N + BSZ - 1) / BSZ;  // 196 buckets
    const int TI = NB * TSTRIDE + 16;    // tails + cursor (zeroed together)

    ushort_t* xb    = (ushort_t*)d_ws;              // [NPAD,128] bf16
    ushort_t* hA    = xb + NPAD * 128;
    ushort_t* hB    = hA + NPAD * 128;
    ushort_t* gbuf  = hB + NPAD * 128;
    ushort_t* wswz  = gbuf + NPAD * 128;            // 3*32768 bf16
    ushort_t* woswz = wswz + 3 * 32768;             // 4096 bf16
    int* flag       = (int*)(woswz + 4096);
    int* tails      = flag + 1;
    int* cursor     = tails + NB * TSTRIDE;         // inside zeroed TI range
    int* endp       = tails + TI;
    int2* rowdeg    = (int2*)(((uintptr_t)endp + 7) & ~(uintptr_t)7);
    uint2* staged   = (uint2*)(rowdeg + N + 8);
    uint_t* csr     = (uint_t*)(staged + (size_t)NB * CAPB);
    (void)ws_size;

    const int ZT = (TI + 255) / 256;
    const int WB = (3 * 32768 + 4096 + 255) / 256;  // 400
    const int XB = (N * 32 + 255) / 256;            // 6250
    const int gB = (E + EPB - 1) / EPB;             // 391
    const int gG = (N + 63) / 64;                   // 782
    const int gA = (N + 3) / 4;                     // 12500
    const int gO = (N + 63) / 64;                   // 782

    SetupArgs sa;
    sa.Wm0 = Wm[0]; sa.Wu0 = Wu[0];
    sa.Wm1 = Wm[1]; sa.Wu1 = Wu[1];
    sa.Wm2 = Wm[2]; sa.Wu2 = Wu[2];
    sa.Wout = Wout; sa.x = x; sa.ei = ei;
    sa.wswz = wswz; sa.woswz = woswz; sa.xb = xb;
    sa.tails = tails; sa.flag = flag;
    sa.N = N; sa.E = E; sa.TI = TI;
    sa.ZT = ZT; sa.WB = WB; sa.XB = XB;
    setup_kernel<<<ZT + 1 + WB + XB, 256, 0, stream>>>(sa);

    bin_kernel<<<gB, 256, 0, stream>>>(ei, ew, flag, tails, staged, E, NB);
    place_kernel<<<NB, 256, 0, stream>>>(staged, tails, cursor, csr, rowdeg, N);

    const ushort_t* hin[3] = {xb, hA, hB};
    ushort_t* hout[3] = {hA, hB, hA};
    for (int l = 0; l < 3; ++l) {
        aggregate_g<<<gA, 256, 0, stream>>>(csr, rowdeg, hin[l], gbuf, N);
        fused_gemm<<<gG, 256, 0, stream>>>(gbuf, hin[l], wswz + (size_t)l * 32768,
                                           bu[l], hout[l], N);
    }
    mfma_gemm_out<<<gO, 256, 0, stream>>>(hA, woswz, bout, out, N);
}